// Round 2
// baseline (598.782 us; speedup 1.0000x reference)
//
#include <hip/hip_runtime.h>

typedef unsigned short u16;
typedef __bf16 bf16;
typedef bf16 bf16x8 __attribute__((ext_vector_type(8)));
typedef float f32x4 __attribute__((ext_vector_type(4)));
typedef u16 u16x8 __attribute__((ext_vector_type(8)));

#define B_ 4
#define S_ 2048
#define H_ 1024
#define NH_ 16
#define HD_ 64
#define M_TOT (B_ * S_)          // 8192
#define N_TOT (3 * H_)           // 3072

__device__ __forceinline__ u16 f2bf(float f) {
    union { float f; unsigned u; } v; v.f = f;
    unsigned r = v.u + 0x7FFFu + ((v.u >> 16) & 1u);
    return (u16)(r >> 16);
}

// ---------------- fp32 -> bf16 conversion ----------------
__global__ __launch_bounds__(256) void cvt_bf16(const float* __restrict__ src,
                                                u16* __restrict__ dst, int n4) {
    int i = blockIdx.x * blockDim.x + threadIdx.x;
    int stride = gridDim.x * blockDim.x;
    for (; i < n4; i += stride) {
        float4 v = ((const float4*)src)[i];
        u16 o0 = f2bf(v.x), o1 = f2bf(v.y), o2 = f2bf(v.z), o3 = f2bf(v.w);
        u16* p = dst + i * 4;
        p[0] = o0; p[1] = o1; p[2] = o2; p[3] = o3;
    }
}

// ---------------- fused QKV GEMM ----------------
// X: [8192][1024] bf16. W: [3072][1024] bf16 = [Wq;Wk;Wv] (rows n-major, K-major).
// Q,K out: [B][NH][S][HD]; V out TRANSPOSED: [B][NH][HD][S]. Q pre-scaled by log2e/8.
#define BK 32
#define LDT 40

__global__ __launch_bounds__(256) void qkv_gemm(
    const u16* __restrict__ X, const u16* __restrict__ W,
    const float* __restrict__ bq, const float* __restrict__ bk, const float* __restrict__ bv,
    u16* __restrict__ Q, u16* __restrict__ Ko, u16* __restrict__ Vt) {
    __shared__ __align__(16) u16 As[128 * LDT];
    __shared__ __align__(16) u16 Bs[128 * LDT];

    const int tid = threadIdx.x;
    const int lane = tid & 63;
    const int wave = tid >> 6;
    const int m0 = blockIdx.y * 128;
    const int n0 = blockIdx.x * 128;
    const int wr = (wave >> 1) * 64;
    const int wc = (wave & 1) * 64;

    f32x4 acc[4][4];
#pragma unroll
    for (int m = 0; m < 4; m++)
#pragma unroll
        for (int n = 0; n < 4; n++) acc[m][n] = (f32x4){0.f, 0.f, 0.f, 0.f};

    const int r0 = tid >> 2;
    const int kq = (tid & 3) * 8;
    const int row_a = lane & 15;
    const int ko = (lane >> 4) * 8;

    for (int k0 = 0; k0 < H_; k0 += BK) {
        __syncthreads();
        *(u16x8*)&As[r0 * LDT + kq]        = *(const u16x8*)&X[(m0 + r0) * H_ + k0 + kq];
        *(u16x8*)&As[(r0 + 64) * LDT + kq] = *(const u16x8*)&X[(m0 + r0 + 64) * H_ + k0 + kq];
        *(u16x8*)&Bs[r0 * LDT + kq]        = *(const u16x8*)&W[(n0 + r0) * H_ + k0 + kq];
        *(u16x8*)&Bs[(r0 + 64) * LDT + kq] = *(const u16x8*)&W[(n0 + r0 + 64) * H_ + k0 + kq];
        __syncthreads();

        bf16x8 a[4], bfr[4];
#pragma unroll
        for (int m = 0; m < 4; m++)
            a[m] = *(const bf16x8*)&As[(wr + m * 16 + row_a) * LDT + ko];
#pragma unroll
        for (int n = 0; n < 4; n++)
            bfr[n] = *(const bf16x8*)&Bs[(wc + n * 16 + row_a) * LDT + ko];
#pragma unroll
        for (int m = 0; m < 4; m++)
#pragma unroll
            for (int n = 0; n < 4; n++)
                acc[m][n] = __builtin_amdgcn_mfma_f32_16x16x32_bf16(a[m], bfr[n], acc[m][n], 0, 0, 0);
    }

    const float QS = 0.125f * 1.44269504f;
#pragma unroll
    for (int n = 0; n < 4; n++) {
        int ng = n0 + wc + n * 16 + (lane & 15);   // 0..3071
        int which = ng >> 10;                       // 0=q 1=k 2=v
        int nn = ng & 1023;
        const float* bp = (which == 0) ? bq : (which == 1) ? bk : bv;
        float bias = bp[nn];
        float scale = (which == 0) ? QS : 1.0f;
        int h = nn >> 6, d = nn & 63;
#pragma unroll
        for (int m = 0; m < 4; m++) {
#pragma unroll
            for (int j = 0; j < 4; j++) {
                int mg = m0 + wr + m * 16 + (lane >> 4) * 4 + j;
                int bb = mg >> 11, s = mg & 2047;
                float v = (acc[m][n][j] + bias) * scale;
                u16 bv16 = f2bf(v);
                if (which == 2) {
                    // V transposed: [B][NH][HD][S]
                    Vt[(((bb * NH_ + h) * HD_) + d) * S_ + s] = bv16;
                } else {
                    u16* dst = (which == 0) ? Q : Ko;
                    dst[(((bb * NH_ + h) * S_) + s) * HD_ + d] = bv16;
                }
            }
        }
    }
}

// ---------------- flash attention ----------------
// Q,K: [B][NH][S][HD] bf16 (Q pre-scaled by log2e/8); Vt: [B][NH][HD][S] bf16.
// mask: [B][S] fp32 additive. out: [B][S][H] fp32.
// 4 independent waves x 16 q-rows; KV tile 64. No barriers; K/V frags direct from global (L2-hit).
#define KVB 64
#define LPV 72

__global__ __launch_bounds__(256) void attn(
    const u16* __restrict__ Q, const u16* __restrict__ K, const u16* __restrict__ Vt,
    const float* __restrict__ mask, float* __restrict__ out) {
    const int head = blockIdx.y;            // 0..63
    const int b = head >> 4, h = head & 15;
    const int q0 = blockIdx.x * 64;
    const int tid = threadIdx.x;
    const int lane = tid & 63;
    const int wave = tid >> 6;

    const u16* Qh = Q + (size_t)head * S_ * HD_;
    const u16* Kh = K + (size_t)head * S_ * HD_;
    const u16* Vh = Vt + (size_t)head * HD_ * S_;   // [d][s]

    __shared__ __align__(16) u16 P[4][16][LPV];

    const int l15 = lane & 15;
    const int g = lane >> 4;
    const int ko = g * 8;
    const int qr = q0 + wave * 16 + l15;
    bf16x8 qf0 = *(const bf16x8*)&Qh[qr * HD_ + ko];
    bf16x8 qf1 = *(const bf16x8*)&Qh[qr * HD_ + 32 + ko];

    f32x4 acc_o[4];
#pragma unroll
    for (int n = 0; n < 4; n++) acc_o[n] = (f32x4){0.f, 0.f, 0.f, 0.f};
    float mj[4], lj[4];
#pragma unroll
    for (int j = 0; j < 4; j++) { mj[j] = -1e30f; lj[j] = 0.f; }

    const float LOG2E = 1.44269504f;
    const float* mrow = mask + b * S_;

    for (int kv0 = 0; kv0 < S_; kv0 += KVB) {
        // ---- QK^T: K-fragments straight from global (L1/L2-resident) ----
        f32x4 s[4];
#pragma unroll
        for (int n = 0; n < 4; n++) {
            const u16* kr = &Kh[(kv0 + n * 16 + l15) * HD_];
            bf16x8 kb0 = *(const bf16x8*)&kr[ko];
            bf16x8 kb1 = *(const bf16x8*)&kr[32 + ko];
            f32x4 c = (f32x4){0.f, 0.f, 0.f, 0.f};
            c = __builtin_amdgcn_mfma_f32_16x16x32_bf16(qf0, kb0, c, 0, 0, 0);
            c = __builtin_amdgcn_mfma_f32_16x16x32_bf16(qf1, kb1, c, 0, 0, 0);
            float mv = mrow[kv0 + n * 16 + l15] * LOG2E;
#pragma unroll
            for (int j = 0; j < 4; j++) c[j] += mv;
            s[n] = c;
        }
        // ---- row max over 64 kv (cols on 16-lane groups) ----
        float tm[4];
#pragma unroll
        for (int j = 0; j < 4; j++)
            tm[j] = fmaxf(fmaxf(s[0][j], s[1][j]), fmaxf(s[2][j], s[3][j]));
#pragma unroll
        for (int dx = 1; dx < 16; dx <<= 1)
#pragma unroll
            for (int j = 0; j < 4; j++) tm[j] = fmaxf(tm[j], __shfl_xor(tm[j], dx, 64));

        // ---- skip-rescale unless max actually grew (THR=0: exactly safe) ----
        int grow = (tm[0] > mj[0]) | (tm[1] > mj[1]) | (tm[2] > mj[2]) | (tm[3] > mj[3]);
        if (__any(grow)) {
#pragma unroll
            for (int j = 0; j < 4; j++) {
                float mn = fmaxf(mj[j], tm[j]);
                float fac = exp2f(mj[j] - mn);
                mj[j] = mn;
                lj[j] *= fac;
#pragma unroll
                for (int n = 0; n < 4; n++) acc_o[n][j] *= fac;
            }
        }

        // ---- P = 2^(s-m) -> per-wave LDS tile [q][kv] ----
        float rs[4] = {0.f, 0.f, 0.f, 0.f};
#pragma unroll
        for (int n = 0; n < 4; n++)
#pragma unroll
            for (int j = 0; j < 4; j++) {
                float p = exp2f(s[n][j] - mj[j]);
                rs[j] += p;
                P[wave][g * 4 + j][n * 16 + l15] = f2bf(p);
            }
#pragma unroll
        for (int dx = 1; dx < 16; dx <<= 1)
#pragma unroll
            for (int j = 0; j < 4; j++) rs[j] += __shfl_xor(rs[j], dx, 64);
#pragma unroll
        for (int j = 0; j < 4; j++) lj[j] += rs[j];

        // ---- PV: P frags from LDS (wave-private, no barrier), V^T frags from global ----
        bf16x8 pf0 = *(const bf16x8*)&P[wave][l15][ko];
        bf16x8 pf1 = *(const bf16x8*)&P[wave][l15][32 + ko];
#pragma unroll
        for (int n = 0; n < 4; n++) {
            const u16* vr = &Vh[(n * 16 + l15) * S_ + kv0];
            bf16x8 vf0 = *(const bf16x8*)&vr[ko];
            bf16x8 vf1 = *(const bf16x8*)&vr[32 + ko];
            acc_o[n] = __builtin_amdgcn_mfma_f32_16x16x32_bf16(pf0, vf0, acc_o[n], 0, 0, 0);
            acc_o[n] = __builtin_amdgcn_mfma_f32_16x16x32_bf16(pf1, vf1, acc_o[n], 0, 0, 0);
        }
    }

    // ---- epilogue ----
#pragma unroll
    for (int n = 0; n < 4; n++)
#pragma unroll
        for (int j = 0; j < 4; j++) {
            int row = q0 + wave * 16 + g * 4 + j;
            float v = acc_o[n][j] / lj[j];
            out[(b * S_ + row) * H_ + h * HD_ + n * 16 + l15] = v;
        }
}

// ---------------- launch ----------------
extern "C" void kernel_launch(void* const* d_in, const int* in_sizes, int n_in,
                              void* d_out, int out_size, void* d_ws, size_t ws_size,
                              hipStream_t stream) {
    const float* hs   = (const float*)d_in[0];
    const float* mask = (const float*)d_in[1];
    const float* wq   = (const float*)d_in[2];
    const float* bq   = (const float*)d_in[3];
    const float* wk   = (const float*)d_in[4];
    const float* bk   = (const float*)d_in[5];
    const float* wv   = (const float*)d_in[6];
    const float* bv   = (const float*)d_in[7];
    float* out = (float*)d_out;

    char* ws = (char*)d_ws;
    u16* Xb = (u16*)ws;                                   // 16 MB
    u16* Wb = (u16*)(ws + 16777216);                      // 6 MB
    u16* Qb = (u16*)(ws + 23068672);                      // 16 MB
    u16* Kb = (u16*)(ws + 39845888);                      // 16 MB
    u16* Vb = (u16*)(ws + 56623104);                      // 16 MB (V^T layout)

    cvt_bf16<<<1024, 256, 0, stream>>>(hs, Xb, (M_TOT * H_) / 4);
    cvt_bf16<<<512, 256, 0, stream>>>(wq, Wb,                (H_ * H_) / 4);
    cvt_bf16<<<512, 256, 0, stream>>>(wk, Wb + H_ * H_,      (H_ * H_) / 4);
    cvt_bf16<<<512, 256, 0, stream>>>(wv, Wb + 2 * H_ * H_,  (H_ * H_) / 4);

    qkv_gemm<<<dim3(N_TOT / 128, M_TOT / 128), 256, 0, stream>>>(
        Xb, Wb, bq, bk, bv, Qb, Kb, Vb);

    attn<<<dim3(S_ / 64, B_ * NH_), 256, 0, stream>>>(Qb, Kb, Vb, mask, out);
}

// Round 3
// 326.530 us; speedup vs baseline: 1.8338x; 1.8338x over previous
//
#include <hip/hip_runtime.h>

typedef unsigned short u16;
typedef __bf16 bf16;
typedef bf16 bf16x8 __attribute__((ext_vector_type(8)));
typedef float f32x4 __attribute__((ext_vector_type(4)));
typedef u16 u16x8 __attribute__((ext_vector_type(8)));
typedef u16 u16x4 __attribute__((ext_vector_type(4)));

#define B_ 4
#define S_ 2048
#define H_ 1024
#define NH_ 16
#define HD_ 64
#define M_TOT (B_ * S_)          // 8192
#define N_TOT (3 * H_)           // 3072

__device__ __forceinline__ u16 f2bf(float f) {
    union { float f; unsigned u; } v; v.f = f;
    unsigned r = v.u + 0x7FFFu + ((v.u >> 16) & 1u);
    return (u16)(r >> 16);
}

__device__ __forceinline__ void gload16(const void* g, void* l) {
    __builtin_amdgcn_global_load_lds(
        (const __attribute__((address_space(1))) void*)g,
        (__attribute__((address_space(3))) void*)l, 16, 0, 0);
}

// ---------------- fp32 -> bf16 conversion ----------------
__global__ __launch_bounds__(256) void cvt_bf16(const float* __restrict__ src,
                                                u16* __restrict__ dst, int n4) {
    int i = blockIdx.x * blockDim.x + threadIdx.x;
    int stride = gridDim.x * blockDim.x;
    for (; i < n4; i += stride) {
        float4 v = ((const float4*)src)[i];
        u16 o0 = f2bf(v.x), o1 = f2bf(v.y), o2 = f2bf(v.z), o3 = f2bf(v.w);
        u16* p = dst + i * 4;
        p[0] = o0; p[1] = o1; p[2] = o2; p[3] = o3;
    }
}

// ---------------- fused QKV GEMM (m97-style staging) ----------------
// X: [8192][1024] bf16. W: [3072][1024] bf16 = [Wq;Wk;Wv].
// Q,K out: [B][NH][S][HD]; V out TRANSPOSED: [B][NH][HD][S]. Q pre-scaled by log2e/8.
__global__ __launch_bounds__(256) void qkv_gemm(
    const u16* __restrict__ X, const u16* __restrict__ W,
    const float* __restrict__ bq, const float* __restrict__ bk, const float* __restrict__ bv,
    u16* __restrict__ Q, u16* __restrict__ Ko, u16* __restrict__ Vt) {
    __shared__ __align__(16) u16 As[128 * 32];   // linear [row][32], 64B rows
    __shared__ __align__(16) u16 Bs[128 * 32];

    const int tid = threadIdx.x;
    const int lane = tid & 63;
    const int wave = tid >> 6;
    const int m0 = blockIdx.y * 128;
    const int n0 = blockIdx.x * 128;
    const int wr = (wave >> 1) * 64;
    const int wc = (wave & 1) * 64;

    f32x4 acc[4][4];
#pragma unroll
    for (int m = 0; m < 4; m++)
#pragma unroll
        for (int n = 0; n < 4; n++) acc[m][n] = (f32x4){0.f, 0.f, 0.f, 0.f};

    // chunk c (of 512 16B chunks per operand): row = c>>2, elems (c&3)*8
    const int ci = wave * 64 + lane;          // pass-0 chunk
    const int ra = ci >> 2, ca = (ci & 3) * 8;
    const u16* gA0 = &X[(size_t)(m0 + ra) * H_ + ca];
    const u16* gA1 = &X[(size_t)(m0 + ra + 64) * H_ + ca];
    const u16* gB0 = &W[(size_t)(n0 + ra) * H_ + ca];
    const u16* gB1 = &W[(size_t)(n0 + ra + 64) * H_ + ca];
    char* lA0 = (char*)As + wave * 1024;
    char* lA1 = (char*)As + 4096 + wave * 1024;
    char* lB0 = (char*)Bs + wave * 1024;
    char* lB1 = (char*)Bs + 4096 + wave * 1024;

    const int row_a = lane & 15;
    const int ko = (lane >> 4) * 8;

    for (int k0 = 0; k0 < H_; k0 += 32) {
        __syncthreads();
        gload16(gA0 + k0, lA0);
        gload16(gA1 + k0, lA1);
        gload16(gB0 + k0, lB0);
        gload16(gB1 + k0, lB1);
        __syncthreads();

        bf16x8 a[4], bfr[4];
#pragma unroll
        for (int m = 0; m < 4; m++)
            a[m] = *(const bf16x8*)&As[(wr + m * 16 + row_a) * 32 + ko];
#pragma unroll
        for (int n = 0; n < 4; n++)
            bfr[n] = *(const bf16x8*)&Bs[(wc + n * 16 + row_a) * 32 + ko];
#pragma unroll
        for (int m = 0; m < 4; m++)
#pragma unroll
            for (int n = 0; n < 4; n++)
                acc[m][n] = __builtin_amdgcn_mfma_f32_16x16x32_bf16(a[m], bfr[n], acc[m][n], 0, 0, 0);
    }

    const float QS = 0.125f * 1.44269504f;
#pragma unroll
    for (int n = 0; n < 4; n++) {
        int ng = n0 + wc + n * 16 + (lane & 15);   // 0..3071
        int which = ng >> 10;                       // 0=q 1=k 2=v
        int nn = ng & 1023;
        const float* bp = (which == 0) ? bq : (which == 1) ? bk : bv;
        float bias = bp[nn];
        float scale = (which == 0) ? QS : 1.0f;
        int h = nn >> 6, d = nn & 63;
#pragma unroll
        for (int m = 0; m < 4; m++) {
            int mg0 = m0 + wr + m * 16 + (lane >> 4) * 4;   // multiple of 4, no batch straddle
            if (which == 2) {
                u16x4 pack;
#pragma unroll
                for (int j = 0; j < 4; j++) pack[j] = f2bf(acc[m][n][j] + bias);
                int bb = mg0 >> 11, s = mg0 & 2047;
                *(u16x4*)&Vt[((((size_t)bb * NH_ + h) * HD_) + d) * S_ + s] = pack;
            } else {
                u16* dst = (which == 0) ? Q : Ko;
#pragma unroll
                for (int j = 0; j < 4; j++) {
                    int mg = mg0 + j;
                    int bb = mg >> 11, s = mg & 2047;
                    float v = (acc[m][n][j] + bias) * scale;
                    dst[((((size_t)bb * NH_ + h) * S_) + s) * HD_ + d] = f2bf(v);
                }
            }
        }
    }
}

// ---------------- flash attention ----------------
// Q,K: [B][NH][S][HD] bf16 (Q pre-scaled by log2e/8); Vt: [B][NH][HD][S] bf16.
// 4 waves x 32 q-rows each = 128 q/block; KV tile 64. K,V^T cooperatively staged.
#define KVB 64
#define LPV 72

__global__ __launch_bounds__(256, 4) void attn(
    const u16* __restrict__ Q, const u16* __restrict__ K, const u16* __restrict__ Vt,
    const float* __restrict__ mask, float* __restrict__ out) {
    const int head = blockIdx.y;            // 0..63
    const int b = head >> 4, h = head & 15;
    const int q0 = blockIdx.x * 128;
    const int tid = threadIdx.x;
    const int lane = tid & 63;
    const int wave = tid >> 6;

    const u16* Qh = Q + (size_t)head * S_ * HD_;
    const u16* Kh = K + (size_t)head * S_ * HD_;
    const u16* Vh = Vt + (size_t)head * HD_ * S_;   // [d][s]

    __shared__ __align__(16) u16 Kl[KVB][LPV];
    __shared__ __align__(16) u16 Vl[HD_][LPV];      // rows = d, cols = kv
    __shared__ __align__(16) u16 P[4][32][LPV];

    const int l15 = lane & 15;
    const int g = lane >> 4;
    const int ko = g * 8;

    bf16x8 qf[2][2];
#pragma unroll
    for (int m = 0; m < 2; m++) {
        int qr = q0 + wave * 32 + m * 16 + l15;
        qf[m][0] = *(const bf16x8*)&Qh[qr * HD_ + ko];
        qf[m][1] = *(const bf16x8*)&Qh[qr * HD_ + 32 + ko];
    }

    f32x4 acc_o[2][4];
#pragma unroll
    for (int m = 0; m < 2; m++)
#pragma unroll
        for (int n = 0; n < 4; n++) acc_o[m][n] = (f32x4){0.f, 0.f, 0.f, 0.f};
    float mj[2][4], lj[2][4];
#pragma unroll
    for (int m = 0; m < 2; m++)
#pragma unroll
        for (int j = 0; j < 4; j++) { mj[m][j] = -1e30f; lj[m][j] = 0.f; }

    const int sr = tid >> 2;           // staging row 0..63
    const int sd = (tid & 3) * 16;     // 0,16,32,48
    const float LOG2E = 1.44269504f;
    const float* mrow = mask + b * S_;

    for (int kv0 = 0; kv0 < S_; kv0 += KVB) {
        __syncthreads();
        *(u16x8*)&Kl[sr][sd]     = *(const u16x8*)&Kh[(kv0 + sr) * HD_ + sd];
        *(u16x8*)&Kl[sr][sd + 8] = *(const u16x8*)&Kh[(kv0 + sr) * HD_ + sd + 8];
        *(u16x8*)&Vl[sr][sd]     = *(const u16x8*)&Vh[sr * S_ + kv0 + sd];
        *(u16x8*)&Vl[sr][sd + 8] = *(const u16x8*)&Vh[sr * S_ + kv0 + sd + 8];
        __syncthreads();

        // ---- QK^T for both m-frags, K frags loaded once ----
        f32x4 s[2][4];
#pragma unroll
        for (int n = 0; n < 4; n++) {
            bf16x8 kb0 = *(const bf16x8*)&Kl[n * 16 + l15][ko];
            bf16x8 kb1 = *(const bf16x8*)&Kl[n * 16 + l15][32 + ko];
            float mv = mrow[kv0 + n * 16 + l15] * LOG2E;
#pragma unroll
            for (int m = 0; m < 2; m++) {
                f32x4 c = (f32x4){0.f, 0.f, 0.f, 0.f};
                c = __builtin_amdgcn_mfma_f32_16x16x32_bf16(qf[m][0], kb0, c, 0, 0, 0);
                c = __builtin_amdgcn_mfma_f32_16x16x32_bf16(qf[m][1], kb1, c, 0, 0, 0);
#pragma unroll
                for (int j = 0; j < 4; j++) c[j] += mv;
                s[m][n] = c;
            }
        }

        // ---- softmax per m-frag ----
#pragma unroll
        for (int m = 0; m < 2; m++) {
            float tm[4];
#pragma unroll
            for (int j = 0; j < 4; j++)
                tm[j] = fmaxf(fmaxf(s[m][0][j], s[m][1][j]), fmaxf(s[m][2][j], s[m][3][j]));
#pragma unroll
            for (int dx = 1; dx < 16; dx <<= 1)
#pragma unroll
                for (int j = 0; j < 4; j++) tm[j] = fmaxf(tm[j], __shfl_xor(tm[j], dx, 64));

            int grow = (tm[0] > mj[m][0]) | (tm[1] > mj[m][1]) |
                       (tm[2] > mj[m][2]) | (tm[3] > mj[m][3]);
            if (__any(grow)) {
#pragma unroll
                for (int j = 0; j < 4; j++) {
                    float mn = fmaxf(mj[m][j], tm[j]);
                    float fac = exp2f(mj[m][j] - mn);
                    mj[m][j] = mn;
                    lj[m][j] *= fac;
#pragma unroll
                    for (int n = 0; n < 4; n++) acc_o[m][n][j] *= fac;
                }
            }

            float rs[4] = {0.f, 0.f, 0.f, 0.f};
#pragma unroll
            for (int n = 0; n < 4; n++)
#pragma unroll
                for (int j = 0; j < 4; j++) {
                    float p = exp2f(s[m][n][j] - mj[m][j]);
                    rs[j] += p;
                    P[wave][m * 16 + g * 4 + j][n * 16 + l15] = f2bf(p);
                }
#pragma unroll
            for (int dx = 1; dx < 16; dx <<= 1)
#pragma unroll
                for (int j = 0; j < 4; j++) rs[j] += __shfl_xor(rs[j], dx, 64);
#pragma unroll
            for (int j = 0; j < 4; j++) lj[m][j] += rs[j];
        }

        // ---- PV: V frags loaded once per n, reused across m ----
        bf16x8 pf[2][2];
#pragma unroll
        for (int m = 0; m < 2; m++) {
            pf[m][0] = *(const bf16x8*)&P[wave][m * 16 + l15][ko];
            pf[m][1] = *(const bf16x8*)&P[wave][m * 16 + l15][32 + ko];
        }
#pragma unroll
        for (int n = 0; n < 4; n++) {
            bf16x8 vf0 = *(const bf16x8*)&Vl[n * 16 + l15][ko];
            bf16x8 vf1 = *(const bf16x8*)&Vl[n * 16 + l15][32 + ko];
#pragma unroll
            for (int m = 0; m < 2; m++) {
                acc_o[m][n] = __builtin_amdgcn_mfma_f32_16x16x32_bf16(pf[m][0], vf0, acc_o[m][n], 0, 0, 0);
                acc_o[m][n] = __builtin_amdgcn_mfma_f32_16x16x32_bf16(pf[m][1], vf1, acc_o[m][n], 0, 0, 0);
            }
        }
    }

    // ---- epilogue ----
#pragma unroll
    for (int m = 0; m < 2; m++)
#pragma unroll
        for (int n = 0; n < 4; n++)
#pragma unroll
            for (int j = 0; j < 4; j++) {
                int row = q0 + wave * 32 + m * 16 + g * 4 + j;
                float v = acc_o[m][n][j] / lj[m][j];
                out[((size_t)b * S_ + row) * H_ + h * HD_ + n * 16 + l15] = v;
            }
}

// ---------------- launch ----------------
extern "C" void kernel_launch(void* const* d_in, const int* in_sizes, int n_in,
                              void* d_out, int out_size, void* d_ws, size_t ws_size,
                              hipStream_t stream) {
    const float* hs   = (const float*)d_in[0];
    const float* mask = (const float*)d_in[1];
    const float* wq   = (const float*)d_in[2];
    const float* bq   = (const float*)d_in[3];
    const float* wk   = (const float*)d_in[4];
    const float* bk   = (const float*)d_in[5];
    const float* wv   = (const float*)d_in[6];
    const float* bv   = (const float*)d_in[7];
    float* out = (float*)d_out;

    char* ws = (char*)d_ws;
    u16* Xb = (u16*)ws;                                   // 16 MB
    u16* Wb = (u16*)(ws + 16777216);                      // 6 MB
    u16* Qb = (u16*)(ws + 23068672);                      // 16 MB
    u16* Kb = (u16*)(ws + 39845888);                      // 16 MB
    u16* Vb = (u16*)(ws + 56623104);                      // 16 MB (V^T layout)

    cvt_bf16<<<1024, 256, 0, stream>>>(hs, Xb, (M_TOT * H_) / 4);
    cvt_bf16<<<512, 256, 0, stream>>>(wq, Wb,                (H_ * H_) / 4);
    cvt_bf16<<<512, 256, 0, stream>>>(wk, Wb + H_ * H_,      (H_ * H_) / 4);
    cvt_bf16<<<512, 256, 0, stream>>>(wv, Wb + 2 * H_ * H_,  (H_ * H_) / 4);

    qkv_gemm<<<dim3(N_TOT / 128, M_TOT / 128), 256, 0, stream>>>(
        Xb, Wb, bq, bk, bv, Qb, Kb, Vb);

    attn<<<dim3(S_ / 128, B_ * NH_), 256, 0, stream>>>(Qb, Kb, Vb, mask, out);
}

// Round 4
// 209.716 us; speedup vs baseline: 2.8552x; 1.5570x over previous
//
#include <hip/hip_runtime.h>

typedef unsigned short u16;
typedef unsigned int u32;
typedef __bf16 bf16;
typedef bf16 bf16x8 __attribute__((ext_vector_type(8)));
typedef float f32x4 __attribute__((ext_vector_type(4)));
typedef float f32x16 __attribute__((ext_vector_type(16)));
typedef u16 u16x8 __attribute__((ext_vector_type(8)));
typedef u16 u16x4 __attribute__((ext_vector_type(4)));
typedef u32 u32x4 __attribute__((ext_vector_type(4)));

#define B_ 4
#define S_ 2048
#define H_ 1024
#define NH_ 16
#define HD_ 64
#define M_TOT (B_ * S_)          // 8192
#define N_TOT (3 * H_)           // 3072

#if __has_builtin(__builtin_amdgcn_exp2f)
#define EXP2(x) __builtin_amdgcn_exp2f(x)
#else
#define EXP2(x) exp2f(x)
#endif

__device__ __forceinline__ u16 f2bf(float f) {
    union { float f; unsigned u; } v; v.f = f;
    unsigned r = v.u + 0x7FFFu + ((v.u >> 16) & 1u);
    return (u16)(r >> 16);
}

__device__ __forceinline__ u32 cvt_pk_bf16(float a, float b) {
    u32 r;
    asm("v_cvt_pk_bf16_f32 %0, %1, %2" : "=v"(r) : "v"(a), "v"(b));
    return r;
}
// v_permlane32_swap_b32: a.row1 <-> b.row0.
// After: a[l<32]=a, a[l>=32]=b[l-32];  b[l<32]=a[l+32], b[l>=32]=b.
__device__ __forceinline__ void perm32swap(u32& a, u32& b) {
    asm volatile("v_permlane32_swap_b32 %0, %1" : "+v"(a), "+v"(b));
}

// ---------------- fp32 -> bf16 conversion ----------------
__global__ __launch_bounds__(256) void cvt_bf16(const float* __restrict__ src,
                                                u16* __restrict__ dst, int n4) {
    int i = blockIdx.x * blockDim.x + threadIdx.x;
    int stride = gridDim.x * blockDim.x;
    for (; i < n4; i += stride) {
        float4 v = ((const float4*)src)[i];
        u16 o0 = f2bf(v.x), o1 = f2bf(v.y), o2 = f2bf(v.z), o3 = f2bf(v.w);
        u16* p = dst + i * 4;
        p[0] = o0; p[1] = o1; p[2] = o2; p[3] = o3;
    }
}

// ---------------- fused QKV GEMM (m97-style staging, unchanged from R3) ----------------
__global__ __launch_bounds__(256) void qkv_gemm(
    const u16* __restrict__ X, const u16* __restrict__ W,
    const float* __restrict__ bq, const float* __restrict__ bk, const float* __restrict__ bv,
    u16* __restrict__ Q, u16* __restrict__ Ko, u16* __restrict__ Vt) {
    __shared__ __align__(16) u16 As[128 * 32];
    __shared__ __align__(16) u16 Bs[128 * 32];

    const int tid = threadIdx.x;
    const int lane = tid & 63;
    const int wave = tid >> 6;
    const int m0 = blockIdx.y * 128;
    const int n0 = blockIdx.x * 128;
    const int wr = (wave >> 1) * 64;
    const int wc = (wave & 1) * 64;

    f32x4 acc[4][4];
#pragma unroll
    for (int m = 0; m < 4; m++)
#pragma unroll
        for (int n = 0; n < 4; n++) acc[m][n] = (f32x4){0.f, 0.f, 0.f, 0.f};

    const int ci = wave * 64 + lane;
    const int ra = ci >> 2, ca = (ci & 3) * 8;
    const u16* gA0 = &X[(size_t)(m0 + ra) * H_ + ca];
    const u16* gA1 = &X[(size_t)(m0 + ra + 64) * H_ + ca];
    const u16* gB0 = &W[(size_t)(n0 + ra) * H_ + ca];
    const u16* gB1 = &W[(size_t)(n0 + ra + 64) * H_ + ca];
    char* lA0 = (char*)As + wave * 1024;
    char* lA1 = (char*)As + 4096 + wave * 1024;
    char* lB0 = (char*)Bs + wave * 1024;
    char* lB1 = (char*)Bs + 4096 + wave * 1024;

    const int row_a = lane & 15;
    const int ko = (lane >> 4) * 8;

    for (int k0 = 0; k0 < H_; k0 += 32) {
        __syncthreads();
        __builtin_amdgcn_global_load_lds((const __attribute__((address_space(1))) void*)(gA0 + k0),
                                         (__attribute__((address_space(3))) void*)lA0, 16, 0, 0);
        __builtin_amdgcn_global_load_lds((const __attribute__((address_space(1))) void*)(gA1 + k0),
                                         (__attribute__((address_space(3))) void*)lA1, 16, 0, 0);
        __builtin_amdgcn_global_load_lds((const __attribute__((address_space(1))) void*)(gB0 + k0),
                                         (__attribute__((address_space(3))) void*)lB0, 16, 0, 0);
        __builtin_amdgcn_global_load_lds((const __attribute__((address_space(1))) void*)(gB1 + k0),
                                         (__attribute__((address_space(3))) void*)lB1, 16, 0, 0);
        __syncthreads();

        bf16x8 a[4], bfr[4];
#pragma unroll
        for (int m = 0; m < 4; m++)
            a[m] = *(const bf16x8*)&As[(wr + m * 16 + row_a) * 32 + ko];
#pragma unroll
        for (int n = 0; n < 4; n++)
            bfr[n] = *(const bf16x8*)&Bs[(wc + n * 16 + row_a) * 32 + ko];
#pragma unroll
        for (int m = 0; m < 4; m++)
#pragma unroll
            for (int n = 0; n < 4; n++)
                acc[m][n] = __builtin_amdgcn_mfma_f32_16x16x32_bf16(a[m], bfr[n], acc[m][n], 0, 0, 0);
    }

    const float QS = 0.125f * 1.44269504f;
#pragma unroll
    for (int n = 0; n < 4; n++) {
        int ng = n0 + wc + n * 16 + (lane & 15);
        int which = ng >> 10;
        int nn = ng & 1023;
        const float* bp = (which == 0) ? bq : (which == 1) ? bk : bv;
        float bias = bp[nn];
        float scale = (which == 0) ? QS : 1.0f;
        int h = nn >> 6, d = nn & 63;
#pragma unroll
        for (int m = 0; m < 4; m++) {
            int mg0 = m0 + wr + m * 16 + (lane >> 4) * 4;
            if (which == 2) {
                u16x4 pack;
#pragma unroll
                for (int j = 0; j < 4; j++) pack[j] = f2bf(acc[m][n][j] + bias);
                int bb = mg0 >> 11, s = mg0 & 2047;
                *(u16x4*)&Vt[((((size_t)bb * NH_ + h) * HD_) + d) * S_ + s] = pack;
            } else {
                u16* dst = (which == 0) ? Q : Ko;
#pragma unroll
                for (int j = 0; j < 4; j++) {
                    int mg = mg0 + j;
                    int bb = mg >> 11, s = mg & 2047;
                    float v = (acc[m][n][j] + bias) * scale;
                    dst[((((size_t)bb * NH_ + h) * S_) + s) * HD_ + d] = f2bf(v);
                }
            }
        }
    }
}

// ---------------- flash attention: swapped QK^T, in-register softmax ----------------
// Q,K: [B][NH][S][HD] bf16 (Q pre-scaled by log2e/8); Vt: [B][NH][HD][S] bf16.
// mask: [B][S] fp32. out: [B][S][H] fp32.
// 4 waves x 32 q-rows (q = lane&31 per wave). KV tile 64, 32x32x16 MFMA.
// S^T[kv][q] = mfma(A=K-tile, B=Q^T); lane holds 32 kv-scores of ONE q-row.
// O^T[d][q] = mfma(A=V^T, B=P^T); P built in-register via cvt_pk + permlane32_swap.
#define KVB 64

__global__ __launch_bounds__(256, 4) void attn(
    const u16* __restrict__ Q, const u16* __restrict__ K, const u16* __restrict__ Vt,
    const float* __restrict__ mask, float* __restrict__ out) {
    const int head = blockIdx.y;
    const int b = head >> 4, h = head & 15;
    const int q0 = blockIdx.x * 128;
    const int tid = threadIdx.x;
    const int lane = tid & 63;
    const int wave = tid >> 6;
    const int l31 = lane & 31;
    const int hi = lane >> 5;

    const u16* Qh = Q + (size_t)head * S_ * HD_;
    const u16* Kh = K + (size_t)head * S_ * HD_;
    const u16* Vh = Vt + (size_t)head * HD_ * S_;   // [d][s]

    __shared__ __align__(16) u16 Kl[KVB * HD_];     // 8KB, XOR-swizzled rows (kv-major)
    __shared__ __align__(16) u16 Vl[HD_ * KVB];     // 8KB, XOR-swizzled rows (d-major)
    __shared__ __align__(16) float ml[S_];          // mask*log2e
    __shared__ int snz;

    // ---- stage mask row once; detect all-zero ----
    if (tid == 0) snz = 0;
    __syncthreads();
    {
        int nz = 0;
        const float4* m4 = (const float4*)(mask + (size_t)b * S_);
        for (int i = tid; i < S_ / 4; i += 256) {
            float4 v = m4[i];
            nz |= (v.x != 0.f) | (v.y != 0.f) | (v.z != 0.f) | (v.w != 0.f);
            f32x4 sv = { v.x * 1.44269504f, v.y * 1.44269504f,
                         v.z * 1.44269504f, v.w * 1.44269504f };
            *(f32x4*)&ml[i * 4] = sv;
        }
        if (__any(nz) && lane == 0) atomicOr(&snz, 1);
    }
    __syncthreads();
    const bool mz = (snz == 0);

    // ---- Q fragments (B-operand): lane holds q=lane&31, d-slice hi*8 + dk*16 ----
    bf16x8 qf[4];
    {
        const u16* qp = &Qh[(size_t)(q0 + wave * 32 + l31) * HD_ + hi * 8];
        qf[0] = *(const bf16x8*)(qp);
        qf[1] = *(const bf16x8*)(qp + 16);
        qf[2] = *(const bf16x8*)(qp + 32);
        qf[3] = *(const bf16x8*)(qp + 48);
    }

    f32x16 oacc[2];
#pragma unroll
    for (int dh = 0; dh < 2; dh++)
#pragma unroll
        for (int i = 0; i < 16; i++) oacc[dh][i] = 0.f;
    float m = -1e30f, l = 0.f;

    // staging addresses
    const int sr = tid >> 2;                         // row 0..63
    const u32 sdB = (u32)((tid & 3) * 32);           // byte offset in 128B row
    const u32 swzS = (u32)((sr & 7) << 4);
    const u32 off0 = ((u32)(sr * 128) + sdB) ^ swzS;
    const u32 off1 = off0 ^ 16u;
    const u16* kSrc = &Kh[(size_t)sr * HD_ + (tid & 3) * 16];
    const u16* vSrc = &Vh[(size_t)sr * S_ + (tid & 3) * 16];
    const u32 swzR = (u32)((l31 & 7) << 4);
    const u32 rowB = (u32)(l31 * 128);

    for (int kv0 = 0; kv0 < S_; kv0 += KVB) {
        __syncthreads();
        {
            const u16* ks = kSrc + (size_t)kv0 * HD_;
            const u16* vs = vSrc + kv0;
            u16x8 a0 = *(const u16x8*)ks;
            u16x8 a1 = *(const u16x8*)(ks + 8);
            u16x8 b0 = *(const u16x8*)vs;
            u16x8 b1 = *(const u16x8*)(vs + 8);
            *(u16x8*)((char*)Kl + off0) = a0;
            *(u16x8*)((char*)Kl + off1) = a1;
            *(u16x8*)((char*)Vl + off0) = b0;
            *(u16x8*)((char*)Vl + off1) = b1;
        }
        __syncthreads();

        // ---- QK^T: S^T[kv][q], 2 kv-groups x 4 d-steps ----
        f32x16 sc[2];
#pragma unroll
        for (int g = 0; g < 2; g++) {
            f32x16 c;
#pragma unroll
            for (int i = 0; i < 16; i++) c[i] = 0.f;
#pragma unroll
            for (int dk = 0; dk < 4; dk++) {
                bf16x8 kf = *(const bf16x8*)((const char*)Kl + g * 4096 + rowB +
                                             (((u32)(dk * 32 + hi * 16)) ^ swzR));
                c = __builtin_amdgcn_mfma_f32_32x32x16_bf16(kf, qf[dk], c, 0, 0, 0);
            }
            sc[g] = c;
        }

        // ---- additive mask (general path; skipped for all-zero mask) ----
        if (!mz) {
#pragma unroll
            for (int g = 0; g < 2; g++)
#pragma unroll
                for (int c4 = 0; c4 < 4; c4++) {
                    f32x4 mk = *(const f32x4*)&ml[kv0 + g * 32 + c4 * 8 + hi * 4];
#pragma unroll
                    for (int e = 0; e < 4; e++) sc[g][c4 * 4 + e] += mk[e];
                }
        }

        // ---- row max (in-lane + partner swap), defer-rescale THR=30 (log2) ----
        float tm = sc[0][0];
#pragma unroll
        for (int i = 1; i < 16; i++) tm = fmaxf(tm, sc[0][i]);
#pragma unroll
        for (int i = 0; i < 16; i++) tm = fmaxf(tm, sc[1][i]);
        tm = fmaxf(tm, __shfl_xor(tm, 32, 64));
        if (tm > m + 30.f) {
            float fac = EXP2(m - tm);
            l *= fac;
#pragma unroll
            for (int dh = 0; dh < 2; dh++)
#pragma unroll
                for (int i = 0; i < 16; i++) oacc[dh][i] *= fac;
            m = tm;
        }

        // ---- P = 2^(s-m) in place; l-sum in-lane ----
        float l0 = 0.f, l1 = 0.f, l2 = 0.f, l3 = 0.f;
#pragma unroll
        for (int g = 0; g < 2; g++)
#pragma unroll
            for (int i = 0; i < 16; i += 4) {
                float p0 = EXP2(sc[g][i + 0] - m);
                float p1 = EXP2(sc[g][i + 1] - m);
                float p2 = EXP2(sc[g][i + 2] - m);
                float p3 = EXP2(sc[g][i + 3] - m);
                sc[g][i + 0] = p0; sc[g][i + 1] = p1;
                sc[g][i + 2] = p2; sc[g][i + 3] = p3;
                l0 += p0; l1 += p1; l2 += p2; l3 += p3;
            }
        l += (l0 + l1) + (l2 + l3);

        // ---- PV: per 16-kv subtile, build P^T B-frag in-register, 2 d-halves ----
#pragma unroll
        for (int s = 0; s < 4; s++) {
            const int g = s >> 1, r8 = (s & 1) * 8;
            u32 pkA0 = cvt_pk_bf16(sc[g][r8 + 0], sc[g][r8 + 1]);
            u32 pkA1 = cvt_pk_bf16(sc[g][r8 + 2], sc[g][r8 + 3]);
            u32 pkB0 = cvt_pk_bf16(sc[g][r8 + 4], sc[g][r8 + 5]);
            u32 pkB1 = cvt_pk_bf16(sc[g][r8 + 6], sc[g][r8 + 7]);
            perm32swap(pkA0, pkB0);   // -> word0, word2
            perm32swap(pkA1, pkB1);   // -> word1, word3
            union { u32x4 w; bf16x8 v; } pu;
            pu.w = (u32x4){ pkA0, pkA1, pkB0, pkB1 };
            bf16x8 pf = pu.v;
#pragma unroll
            for (int dh = 0; dh < 2; dh++) {
                bf16x8 vf = *(const bf16x8*)((const char*)Vl + dh * 4096 + rowB +
                                             (((u32)(s * 32 + hi * 16)) ^ swzR));
                oacc[dh] = __builtin_amdgcn_mfma_f32_32x32x16_bf16(vf, pf, oacc[dh], 0, 0, 0);
            }
        }
    }

    // ---- epilogue: lane owns q-row; O^T regs -> out[b][q][h*64+d] ----
    float lt = l + __shfl_xor(l, 32, 64);
    float inv = 1.0f / lt;
    const int q = q0 + wave * 32 + l31;
    float* orow = out + ((size_t)b * S_ + q) * H_ + h * HD_;
#pragma unroll
    for (int dh = 0; dh < 2; dh++)
#pragma unroll
        for (int c4 = 0; c4 < 4; c4++) {
            f32x4 v;
#pragma unroll
            for (int e = 0; e < 4; e++) v[e] = oacc[dh][c4 * 4 + e] * inv;
            *(f32x4*)&orow[dh * 32 + c4 * 8 + hi * 4] = v;
        }
}

// ---------------- launch ----------------
extern "C" void kernel_launch(void* const* d_in, const int* in_sizes, int n_in,
                              void* d_out, int out_size, void* d_ws, size_t ws_size,
                              hipStream_t stream) {
    const float* hs   = (const float*)d_in[0];
    const float* mask = (const float*)d_in[1];
    const float* wq   = (const float*)d_in[2];
    const float* bq   = (const float*)d_in[3];
    const float* wk   = (const float*)d_in[4];
    const float* bk   = (const float*)d_in[5];
    const float* wv   = (const float*)d_in[6];
    const float* bv   = (const float*)d_in[7];
    float* out = (float*)d_out;

    char* ws = (char*)d_ws;
    u16* Xb = (u16*)ws;                                   // 16 MB
    u16* Wb = (u16*)(ws + 16777216);                      // 6 MB
    u16* Qb = (u16*)(ws + 23068672);                      // 16 MB
    u16* Kb = (u16*)(ws + 39845888);                      // 16 MB
    u16* Vb = (u16*)(ws + 56623104);                      // 16 MB (V^T layout)

    cvt_bf16<<<1024, 256, 0, stream>>>(hs, Xb, (M_TOT * H_) / 4);
    cvt_bf16<<<512, 256, 0, stream>>>(wq, Wb,                (H_ * H_) / 4);
    cvt_bf16<<<512, 256, 0, stream>>>(wk, Wb + H_ * H_,      (H_ * H_) / 4);
    cvt_bf16<<<512, 256, 0, stream>>>(wv, Wb + 2 * H_ * H_,  (H_ * H_) / 4);

    qkv_gemm<<<dim3(N_TOT / 128, M_TOT / 128), 256, 0, stream>>>(
        Xb, Wb, bq, bk, bv, Qb, Kb, Vb);

    attn<<<dim3(S_ / 128, B_ * NH_), 256, 0, stream>>>(Qb, Kb, Vb, mask, out);
}